// Round 5
// baseline (269.925 us; speedup 1.0000x reference)
//
#include <hip/hip_runtime.h>
#include <hip/hip_bf16.h>

#define BATCH 16
#define NV    20000
#define FIN   64
#define NCOUT 64
#define NK    16
#define TOTROWS  (BATCH * NV)      // 320000
#define NTILES   (TOTROWS / 16)    // 20000 row-tiles of 16
#define TPX      (NTILES / 8)      // 2500 tiles per XCD (= 2 batches)
#define TPB      (NV / 16)         // 1250 tiles per batch

typedef __attribute__((ext_vector_type(8))) short bf16x8;   // 8 bf16 (4 VGPRs)
typedef __attribute__((ext_vector_type(4))) float f32x4;    // MFMA acc / NT ld-st
typedef __attribute__((ext_vector_type(4))) unsigned short u16x4;
typedef __attribute__((ext_vector_type(2))) unsigned int u32x2;

__device__ __forceinline__ short f2b(float f) {
    __hip_bfloat16 h = __float2bfloat16(f);   // RTNE
    return __builtin_bit_cast(short, h);
}

// ---------------------------------------------------------------------------
// K1: z = x @ (Wn/16), bf16, into ws. Pure producer pass.
//   read x 82 MB (nontemporal: don't evict z from L2), write z 41 MB (cached:
//   the tail stays warm for K2, which walks DESCENDING to meet it).
// Col-tile t covers cols {4m+t}; z store is one dwordx2 per row.
// ---------------------------------------------------------------------------
__global__ __launch_bounds__(256, 4) void convnet_zpass(
    const float* __restrict__ x,      // (320000, 64)
    const float* __restrict__ Wn,     // (64, 64)
    __hip_bfloat16* __restrict__ z)   // (320000, 64) bf16 [ws]
{
    const int lane = threadIdx.x & 63;
    const int m    = lane & 15;
    const int quad = lane >> 4;

    // B frags: frag[j] = Wn[k][4m + t]/16, k = 32h + quad*8 + j.
    bf16x8 bn[4][2];
#pragma unroll
    for (int t = 0; t < 4; ++t) {
        const int c = 4 * m + t;
#pragma unroll
        for (int h = 0; h < 2; ++h) {
            bf16x8 fr;
#pragma unroll
            for (int j = 0; j < 8; ++j) {
                const int f = 32 * h + quad * 8 + j;
                fr[j] = f2b(Wn[f * NCOUT + c] * (1.0f / 16.0f));
            }
            bn[t][h] = fr;
        }
    }

    const int xcd = blockIdx.x & 7;
    const int bi  = blockIdx.x >> 3;
    const int wl  = bi * 4 + ((int)threadIdx.x >> 6);
    const int WPX = (gridDim.x >> 3) * 4;              // 512 waves/xcd

    for (int t0 = wl; t0 < TPX; t0 += WPX) {
        const int rt = __builtin_amdgcn_readfirstlane(xcd * TPX + t0);
        const float* xt =
            x + (size_t)rt * (16 * FIN) + (size_t)m * FIN + quad * 8;

        const f32x4 La0 = __builtin_nontemporal_load((const f32x4*)xt);
        const f32x4 La1 = __builtin_nontemporal_load((const f32x4*)xt + 1);
        const f32x4 Lb0 = __builtin_nontemporal_load((const f32x4*)(xt + 32));
        const f32x4 Lb1 = __builtin_nontemporal_load((const f32x4*)(xt + 32) + 1);

        bf16x8 af0, af1;
        af0[0] = f2b(La0.x); af0[1] = f2b(La0.y); af0[2] = f2b(La0.z); af0[3] = f2b(La0.w);
        af0[4] = f2b(La1.x); af0[5] = f2b(La1.y); af0[6] = f2b(La1.z); af0[7] = f2b(La1.w);
        af1[0] = f2b(Lb0.x); af1[1] = f2b(Lb0.y); af1[2] = f2b(Lb0.z); af1[3] = f2b(Lb0.w);
        af1[4] = f2b(Lb1.x); af1[5] = f2b(Lb1.y); af1[6] = f2b(Lb1.z); af1[7] = f2b(Lb1.w);

        f32x4 acc[4];
#pragma unroll
        for (int t = 0; t < 4; ++t) acc[t] = (f32x4){0.f, 0.f, 0.f, 0.f};
#pragma unroll
        for (int t = 0; t < 4; ++t)
            acc[t] = __builtin_amdgcn_mfma_f32_16x16x32_bf16(af0, bn[t][0], acc[t], 0, 0, 0);
#pragma unroll
        for (int t = 0; t < 4; ++t)
            acc[t] = __builtin_amdgcn_mfma_f32_16x16x32_bf16(af1, bn[t][1], acc[t], 0, 0, 0);

        const size_t rbase = (size_t)rt * 16 + quad * 4;
#pragma unroll
        for (int r = 0; r < 4; ++r) {
            const size_t orow = (rbase + r) * NCOUT + 4 * m;
            u16x4 zz;
            zz.x = (unsigned short)f2b(acc[0][r]);
            zz.y = (unsigned short)f2b(acc[1][r]);
            zz.z = (unsigned short)f2b(acc[2][r]);
            zz.w = (unsigned short)f2b(acc[3][r]);
            *(u16x4*)(z + orow) = zz;
        }
    }
}

// ---------------------------------------------------------------------------
// K2: out = x@Wx + bias + gather(z).  Fused: the MFMA recompute of p gives
// the latency-bound gather work to hide under, and out is written ONCE
// (kills the 164 MB out round-trip of the old 2-pass split).
// Gather layout == MFMA C/D layout: lane (m, quad) owns rows quad*4+r,
// cols 4m..4m+3 -> per (r,k): one dwordx2 from z row nbr[v,k] at byte col
// m*8; wave covers 4 rows x 128 B contiguous per instr (proven shape).
// Gathered bf16 values accumulate straight into acc[t][r].
// x loads + out stores nontemporal (protect the 2.56 MB z window in L2);
// tiles walked DESCENDING per XCD so K2 starts on K1's still-warm z tail.
// ---------------------------------------------------------------------------
__global__ __launch_bounds__(256, 4) void convnet_fused(
    const float* __restrict__ x,      // (320000, 64)
    const float* __restrict__ Wx,     // (64, 64)
    const float* __restrict__ bias,   // (64)
    const int* __restrict__ nbr,      // (20000, 16), values in [0, V]
    const __hip_bfloat16* __restrict__ z,  // (320000, 64) bf16
    float* __restrict__ out)          // (320000, 64) fp32
{
    const int lane = threadIdx.x & 63;
    const int m    = lane & 15;
    const int quad = lane >> 4;

    bf16x8 bx[4][2];
#pragma unroll
    for (int t = 0; t < 4; ++t) {
        const int c = 4 * m + t;
#pragma unroll
        for (int h = 0; h < 2; ++h) {
            bf16x8 fr;
#pragma unroll
            for (int j = 0; j < 8; ++j) {
                const int f = 32 * h + quad * 8 + j;
                fr[j] = f2b(Wx[f * NCOUT + c]);
            }
            bx[t][h] = fr;
        }
    }
    float bias_q[4];
#pragma unroll
    for (int t = 0; t < 4; ++t) bias_q[t] = bias[4 * m + t];

    const int xcd = blockIdx.x & 7;
    const int bi  = blockIdx.x >> 3;
    const int wl  = bi * 4 + ((int)threadIdx.x >> 6);
    const int WPX = (gridDim.x >> 3) * 4;              // 512 waves/xcd

    // descending walk: start where K1 finished (warm z in this XCD's L2)
    for (int t0 = TPX - 1 - wl; t0 >= 0; t0 -= WPX) {
        const int t0u = __builtin_amdgcn_readfirstlane(t0);
        const int rt  = xcd * TPX + t0u;
        const int blh = (t0u >= TPB) ? 1 : 0;
        const int b   = 2 * xcd + blh;
        const int v0  = (t0u - blh * TPB) * 16;        // in-batch first row

        const float* xt =
            x + (size_t)rt * (16 * FIN) + (size_t)m * FIN + quad * 8;
        const f32x4 La0 = __builtin_nontemporal_load((const f32x4*)xt);
        const f32x4 La1 = __builtin_nontemporal_load((const f32x4*)xt + 1);
        const f32x4 Lb0 = __builtin_nontemporal_load((const f32x4*)(xt + 32));
        const f32x4 Lb1 = __builtin_nontemporal_load((const f32x4*)(xt + 32) + 1);

        bf16x8 af0, af1;
        af0[0] = f2b(La0.x); af0[1] = f2b(La0.y); af0[2] = f2b(La0.z); af0[3] = f2b(La0.w);
        af0[4] = f2b(La1.x); af0[5] = f2b(La1.y); af0[6] = f2b(La1.z); af0[7] = f2b(La1.w);
        af1[0] = f2b(Lb0.x); af1[1] = f2b(Lb0.y); af1[2] = f2b(Lb0.z); af1[3] = f2b(Lb0.w);
        af1[4] = f2b(Lb1.x); af1[5] = f2b(Lb1.y); af1[6] = f2b(Lb1.z); af1[7] = f2b(Lb1.w);

        f32x4 acc[4];
#pragma unroll
        for (int t = 0; t < 4; ++t) acc[t] = (f32x4){0.f, 0.f, 0.f, 0.f};
#pragma unroll
        for (int t = 0; t < 4; ++t)
            acc[t] = __builtin_amdgcn_mfma_f32_16x16x32_bf16(af0, bx[t][0], acc[t], 0, 0, 0);
#pragma unroll
        for (int t = 0; t < 4; ++t)
            acc[t] = __builtin_amdgcn_mfma_f32_16x16x32_bf16(af1, bx[t][1], acc[t], 0, 0, 0);

        // gather 16 neighbors for each of this lane's 4 rows, straight into acc
        const char* zb = (const char*)z + (size_t)b * (NV * 128);  // batch base
        const int zcol = m * 8;
#pragma unroll
        for (int r = 0; r < 4; ++r) {
            const int v = v0 + quad * 4 + r;           // in-batch row (per-lane)
            const int4* nb4 = (const int4*)nbr + (size_t)v * 4;
            const int4 i0 = nb4[0];
            const int4 i1 = nb4[1];
            const int4 i2 = nb4[2];
            const int4 i3 = nb4[3];
            int id[NK];
            id[0]  = i0.x; id[1]  = i0.y; id[2]  = i0.z; id[3]  = i0.w;
            id[4]  = i1.x; id[5]  = i1.y; id[6]  = i1.z; id[7]  = i1.w;
            id[8]  = i2.x; id[9]  = i2.y; id[10] = i2.z; id[11] = i2.w;
            id[12] = i3.x; id[13] = i3.y; id[14] = i3.z; id[15] = i3.w;

            float a0 = 0.f, a1 = 0.f, a2 = 0.f, a3 = 0.f;
#pragma unroll
            for (int k = 0; k < NK; ++k) {
                const int idx = id[k];
                int sel = idx - 1;
                sel = sel < 0 ? 0 : sel;               // clamp pad (masked below)
                const u32x2 d =
                    *(const u32x2*)(zb + (size_t)(unsigned)(sel * 128 + zcol));
                const unsigned dx = idx ? d.x : 0u;
                const unsigned dy = idx ? d.y : 0u;
                a0 += __builtin_bit_cast(float, dx << 16);
                a1 += __builtin_bit_cast(float, dx & 0xFFFF0000u);
                a2 += __builtin_bit_cast(float, dy << 16);
                a3 += __builtin_bit_cast(float, dy & 0xFFFF0000u);
            }
            acc[0][r] += a0;
            acc[1][r] += a1;
            acc[2][r] += a2;
            acc[3][r] += a3;
        }

        const size_t rbase = (size_t)rt * 16 + quad * 4;
#pragma unroll
        for (int r = 0; r < 4; ++r) {
            const size_t orow = (rbase + r) * NCOUT + 4 * m;
            f32x4 o;
            o.x = acc[0][r] + bias_q[0];
            o.y = acc[1][r] + bias_q[1];
            o.z = acc[2][r] + bias_q[2];
            o.w = acc[3][r] + bias_q[3];
            __builtin_nontemporal_store(o, (f32x4*)(out + orow));
        }
    }
}

extern "C" void kernel_launch(void* const* d_in, const int* in_sizes, int n_in,
                              void* d_out, int out_size, void* d_ws, size_t ws_size,
                              hipStream_t stream) {
    const float* x    = (const float*)d_in[0];
    const float* Wx   = (const float*)d_in[1];
    const float* Wn   = (const float*)d_in[2];
    const float* bias = (const float*)d_in[3];
    const int*   nbr  = (const int*)d_in[4];
    float* out = (float*)d_out;

    __hip_bfloat16* z = (__hip_bfloat16*)d_ws;   // 40.96 MB (fits ws)

    hipLaunchKernelGGL(convnet_zpass, dim3(1024), dim3(256), 0, stream,
                       x, Wn, z);
    hipLaunchKernelGGL(convnet_fused, dim3(1024), dim3(256), 0, stream,
                       x, Wx, bias, nbr, z, out);
}